// Round 7
// baseline (177.298 us; speedup 1.0000x reference)
//
#include <hip/hip_runtime.h>
#include <hip/hip_bf16.h>

typedef __bf16 bf16x8 __attribute__((ext_vector_type(8)));
typedef float f32x4 __attribute__((ext_vector_type(4)));

typedef __attribute__((address_space(1))) void GAS;
typedef __attribute__((address_space(3))) void LAS;
#define GLOAD16(gp, lp) __builtin_amdgcn_global_load_lds((GAS*)(gp), (LAS*)(lp), 16, 0, 0)

#define NB 4096
#define NDU 1024   // concat [hi | lo] width
#define BK 32
#define NSTEP 32   // 1024 / 32
#define NTI 32     // 4096 / 128 tiles per dim
#define NBLK2 528  // upper-triangular tiles: 32*33/2
#define PSTR 576   // partial-row stride (64*9, zero-padded)

// ---------------- Kernel 1: row-normalize + split into u = [hi | lo]; zero part/ticket ----------------
__global__ __launch_bounds__(256) void nrm_split_k(const float* __restrict__ x,
                                                   __bf16* __restrict__ u,
                                                   float* __restrict__ part,
                                                   int* __restrict__ ticket) {
    if (blockIdx.x < 20) {
        for (int i = threadIdx.x; i < PSTR; i += 256) part[blockIdx.x * PSTR + i] = 0.0f;
    }
    if (blockIdx.x == 20 && threadIdx.x == 0) *ticket = 0;
    const int wid = threadIdx.x >> 6, lane = threadIdx.x & 63;
    const int row = blockIdx.x * 4 + wid;
    const float4* xr = reinterpret_cast<const float4*>(x + (size_t)row * 512);
    float4 v0 = xr[lane * 2 + 0];
    float4 v1 = xr[lane * 2 + 1];
    float xv[8] = {v0.x, v0.y, v0.z, v0.w, v1.x, v1.y, v1.z, v1.w};
    float ss = 0.0f;
#pragma unroll
    for (int j = 0; j < 8; ++j) ss += xv[j] * xv[j];
#pragma unroll
    for (int off = 32; off > 0; off >>= 1) ss += __shfl_xor(ss, off);
    const float rn = 1.0f / fmaxf(sqrtf(ss), 1e-12f);
    bf16x8 h, l;
#pragma unroll
    for (int j = 0; j < 8; ++j) {
        float xn = xv[j] * rn;
        __bf16 hb = (__bf16)xn;
        h[j] = hb;
        l[j] = (__bf16)(xn - (float)hb);  // xn == hi + lo to ~2^-17
    }
    reinterpret_cast<bf16x8*>(u + (size_t)row * NDU)[lane] = h;
    reinterpret_cast<bf16x8*>(u + (size_t)row * NDU + 512)[lane] = l;
}

// ------- Kernel 2: 128^2-tile upper-tri GEMM (K=1024, m97 structure) + histogram + finalize -------
__global__ __launch_bounds__(256) void gemm_stat_k(const __bf16* __restrict__ u,
                                                   const int* __restrict__ targets,
                                                   const float* __restrict__ acc_sum,
                                                   float* __restrict__ part,
                                                   int* __restrict__ ticket,
                                                   float* __restrict__ out) {
    __shared__ __align__(16) __bf16 lds[2][2][128 * BK];  // [buf][A/B][128 rows x 32 cols], 32 KB
    __shared__ int tgtR[128], tgtC[128];
    __shared__ float red_s[4][10], red_c[4][10];
    __shared__ float tot[20];
    __shared__ int is_last;

    // XCD-chunked bijective swizzle (528 = 8 * 66), then upper-tri decode
    const int s = (blockIdx.x & 7) * 66 + (blockIdx.x >> 3);
    int by = (int)((65.0f - sqrtf((float)(4225 - 8 * s))) * 0.5f);
    int base = 32 * by - ((by * (by - 1)) >> 1);
    if (s < base) { --by; base = 32 * by - ((by * (by - 1)) >> 1); }
    else if (s >= base + (NTI - by)) { ++by; base = 32 * by - ((by * (by - 1)) >> 1); }
    const int bx = by + (s - base);
    const int row0 = by * 128, col0 = bx * 128;
    const float wgt = (by == bx) ? 1.0f : 2.0f;

    const int tid = threadIdx.x, lane = tid & 63;
    const int wid = tid >> 6, wr = wid >> 1, wc = wid & 1;  // 2 x 2 waves

    if (tid < 128) tgtR[tid] = targets[row0 + tid];
    else           tgtC[tid - 128] = targets[col0 + tid - 128];

    // staging: each matrix tile = 128x32 bf16 = 512 x 16B chunks; thread owns chunks tid, tid+256
    // LDS rows are 64 B (4 chunks); swizzle chunk c -> c ^ ((row>>1)&3) (2-way bank aliasing = free)
    const int r0 = tid >> 2,          c0 = tid & 3;
    const int r1 = (tid + 256) >> 2,  c1 = tid & 3;  // (tid+256)&3 == tid&3
    const int sc0 = (c0 ^ ((r0 >> 1) & 3)) * 8;
    const int sc1 = (c1 ^ ((r1 >> 1) & 3)) * 8;
    const __bf16* Aq0 = u + (size_t)(row0 + r0) * NDU + sc0;
    const __bf16* Aq1 = u + (size_t)(row0 + r1) * NDU + sc1;
    const __bf16* Bq0 = u + (size_t)(col0 + r0) * NDU + sc0;
    const __bf16* Bq1 = u + (size_t)(col0 + r1) * NDU + sc1;
    const int d0 = tid * 8, d1 = (tid + 256) * 8;  // linear LDS dests (16B per thread slot)

    auto STAGE = [&](int t) {
        const int buf = t & 1, kc = t * BK;
        GLOAD16(Aq0 + kc, &lds[buf][0][d0]);
        GLOAD16(Aq1 + kc, &lds[buf][0][d1]);
        GLOAD16(Bq0 + kc, &lds[buf][1][d0]);
        GLOAD16(Bq1 + kc, &lds[buf][1][d1]);
    };

    // fragment read offsets: row*32 + swizzled k-chunk
    const int fr = lane & 15, hi16 = lane >> 4;
    const int kb_sw = ((hi16 ^ ((fr >> 1) & 3))) * 8;
    int rowA[4], rowB[4];
#pragma unroll
    for (int m = 0; m < 4; ++m) rowA[m] = (wr * 64 + m * 16 + fr) * BK + kb_sw;
#pragma unroll
    for (int n = 0; n < 4; ++n) rowB[n] = (wc * 64 + n * 16 + fr) * BK + kb_sw;

    const f32x4 fzero = {0.0f, 0.0f, 0.0f, 0.0f};
    f32x4 acc[4][4];
#pragma unroll
    for (int m = 0; m < 4; ++m)
#pragma unroll
        for (int n = 0; n < 4; ++n) acc[m][n] = fzero;

    STAGE(0);
    __syncthreads();

    for (int t = 0; t < NSTEP; ++t) {
        if (t + 1 < NSTEP) STAGE(t + 1);
        const int buf = t & 1;
        const __bf16* lA = &lds[buf][0][0];
        const __bf16* lB = &lds[buf][1][0];
        bf16x8 af[4], bf[4];
#pragma unroll
        for (int m = 0; m < 4; ++m) af[m] = *reinterpret_cast<const bf16x8*>(lA + rowA[m]);
#pragma unroll
        for (int n = 0; n < 4; ++n) bf[n] = *reinterpret_cast<const bf16x8*>(lB + rowB[n]);
#pragma unroll
        for (int m = 0; m < 4; ++m)
#pragma unroll
            for (int n = 0; n < 4; ++n)
                acc[m][n] = __builtin_amdgcn_mfma_f32_16x16x32_bf16(af[m], bf[n], acc[m][n], 0, 0, 0);
        __syncthreads();  // drains vmcnt: next tile resident; all reads of buf retired
    }

    // ---- epilogue: per-lane histogram of g=|cos-label| over 64 elements ----
    // C/D 16x16 layout: col = lane&15, row = (lane>>4)*4 + reg
    int tcv[4];
#pragma unroll
    for (int n = 0; n < 4; ++n) tcv[n] = tgtC[wc * 64 + n * 16 + fr];

    constexpr float E[11] = {0.0f, 0.1f, 0.2f, 0.3f, 0.4f, 0.5f,
                             0.6f, 0.7f, 0.8f, 0.9f, 1.0f + 1e-6f};
    float sacc[10], cacc[10];
#pragma unroll
    for (int b = 0; b < 10; ++b) { sacc[b] = 0.0f; cacc[b] = 0.0f; }

    const int rB = wr * 64 + hi16 * 4;
#pragma unroll
    for (int m = 0; m < 4; ++m) {
        int trv[4];
#pragma unroll
        for (int r = 0; r < 4; ++r) trv[r] = tgtR[rB + m * 16 + r];
#pragma unroll
        for (int n = 0; n < 4; ++n) {
            f32x4 v = acc[m][n];
            const int tc = tcv[n];
#pragma unroll
            for (int r = 0; r < 4; ++r) {
                const float label = (trv[r] == tc) ? 1.0f : 0.0f;
                const float g = fabsf(v[r] - label);
                const float g2 = g * g;
                bool prev = true;
#pragma unroll
                for (int b = 0; b < 10; ++b) {
                    const bool ge = (g >= E[b + 1]);
                    const bool in = prev && (!ge);
                    sacc[b] += in ? g2 : 0.0f;
                    cacc[b] += in ? 1.0f : 0.0f;
                    prev = ge;
                }
            }
        }
    }

#pragma unroll
    for (int b = 0; b < 10; ++b) {
        float sv = sacc[b], cv = cacc[b];
#pragma unroll
        for (int off = 32; off > 0; off >>= 1) {
            sv += __shfl_xor(sv, off);
            cv += __shfl_xor(cv, off);
        }
        if (lane == 0) { red_s[wid][b] = sv * wgt; red_c[wid][b] = cv * wgt; }
    }
    __syncthreads();

    // contention-free partials: device-scope stores to distinct slots
    if (tid < 10) {
        float sv = 0.0f, cv = 0.0f;
#pragma unroll
        for (int w = 0; w < 4; ++w) { sv += red_s[w][tid]; cv += red_c[w][tid]; }
        __hip_atomic_store(&part[tid * PSTR + s], sv,
                           __ATOMIC_RELAXED, __HIP_MEMORY_SCOPE_AGENT);
        __hip_atomic_store(&part[(10 + tid) * PSTR + s], cv,
                           __ATOMIC_RELAXED, __HIP_MEMORY_SCOPE_AGENT);
    }
    __syncthreads();

    if (tid == 0) {
        int old = __hip_atomic_fetch_add(ticket, 1, __ATOMIC_ACQ_REL,
                                         __HIP_MEMORY_SCOPE_AGENT);
        is_last = (old == NBLK2 - 1) ? 1 : 0;
    }
    __syncthreads();

    // last block: reduce 20 x 528 partials (rows zero-padded to 576), compute loss
    if (is_last) {
        for (int b = wid; b < 20; b += 4) {
            float v = 0.0f;
#pragma unroll
            for (int j = 0; j < 9; ++j)
                v += __hip_atomic_load(&part[b * PSTR + lane + 64 * j],
                                       __ATOMIC_RELAXED, __HIP_MEMORY_SCOPE_AGENT);
#pragma unroll
            for (int off = 32; off > 0; off >>= 1) v += __shfl_xor(v, off);
            if (lane == 0) tot[b] = v;
        }
        __syncthreads();
        if (tid == 0) {
            const float totN = 16777216.0f;  // 4096^2
            double num = 0.0, valid = 0.0;
#pragma unroll
            for (int b = 0; b < 10; ++b) {
                float cnt = tot[10 + b];
                float accn = 0.5f * acc_sum[b] + 0.5f * cnt;
                float w = totN / (accn + 1e-6f);
                num += (double)tot[b] * (double)w;
                valid += (double)cnt;
            }
            out[0] = (valid > 0.0) ? (float)(num / valid / 16777216.0) : 0.0f;
        }
    }
}

extern "C" void kernel_launch(void* const* d_in, const int* in_sizes, int n_in,
                              void* d_out, int out_size, void* d_ws, size_t ws_size,
                              hipStream_t stream) {
    const float* x = (const float*)d_in[0];
    const float* acc_sum = (const float*)d_in[1];
    const int* targets = (const int*)d_in[2];
    float* out = (float*)d_out;

    char* ws = (char*)d_ws;
    __bf16* u = (__bf16*)ws;                                         // 4096 x 1024 bf16 = 8 MB
    float* part = (float*)(ws + (size_t)NB * NDU * sizeof(__bf16));  // 20 x 576 partials
    int* ticket = (int*)(part + 20 * PSTR);

    nrm_split_k<<<NB / 4, 256, 0, stream>>>(x, u, part, ticket);
    gemm_stat_k<<<NBLK2, 256, 0, stream>>>(u, targets, acc_sum, part, ticket, out);
}

// Round 8
// 159.416 us; speedup vs baseline: 1.1122x; 1.1122x over previous
//
#include <hip/hip_runtime.h>
#include <hip/hip_bf16.h>

typedef __bf16 bf16x8 __attribute__((ext_vector_type(8)));
typedef float f32x4 __attribute__((ext_vector_type(4)));
typedef unsigned int u32x4 __attribute__((ext_vector_type(4)));

typedef __attribute__((address_space(1))) void GAS;
typedef __attribute__((address_space(3))) void LAS;
#define GLOAD16(gp, lp) __builtin_amdgcn_global_load_lds((GAS*)(gp), (LAS*)(lp), 16, 0, 0)

#define NB 4096
#define NDU 1024  // concat [hi | lo] width
#define NKT 16    // 1024 / 64
#define NBLK 256

// ---------------- Kernel 1: row-normalize + split into u = [hi | lo]; zero part/ticket ----------------
// u is written NONTEMPORALLY so it lands clean in L3/memory instead of dirty in this
// XCD's private L2 (cross-XCD dirty-line resolution is the suspected ~110us latency wall).
__global__ __launch_bounds__(256) void nrm_split_k(const float* __restrict__ x,
                                                   __bf16* __restrict__ u,
                                                   float* __restrict__ part,
                                                   int* __restrict__ ticket) {
    if (blockIdx.x < 20) part[blockIdx.x * NBLK + threadIdx.x] = 0.0f;  // 20 x 256 partials
    if (blockIdx.x == 20 && threadIdx.x == 0) *ticket = 0;
    const int wid = threadIdx.x >> 6, lane = threadIdx.x & 63;
    const int row = blockIdx.x * 4 + wid;
    const float4* xr = reinterpret_cast<const float4*>(x + (size_t)row * 512);
    float4 v0 = xr[lane * 2 + 0];
    float4 v1 = xr[lane * 2 + 1];
    float xv[8] = {v0.x, v0.y, v0.z, v0.w, v1.x, v1.y, v1.z, v1.w};
    float ss = 0.0f;
#pragma unroll
    for (int j = 0; j < 8; ++j) ss += xv[j] * xv[j];
#pragma unroll
    for (int off = 32; off > 0; off >>= 1) ss += __shfl_xor(ss, off);
    const float rn = 1.0f / fmaxf(sqrtf(ss), 1e-12f);
    bf16x8 h, l;
#pragma unroll
    for (int j = 0; j < 8; ++j) {
        float xn = xv[j] * rn;
        __bf16 hb = (__bf16)xn;
        h[j] = hb;
        l[j] = (__bf16)(xn - (float)hb);  // xn == hi + lo to ~2^-17
    }
    u32x4* dh = reinterpret_cast<u32x4*>(u + (size_t)row * NDU) + lane;
    u32x4* dl = reinterpret_cast<u32x4*>(u + (size_t)row * NDU + 512) + lane;
    __builtin_nontemporal_store(*reinterpret_cast<u32x4*>(&h), dh);
    __builtin_nontemporal_store(*reinterpret_cast<u32x4*>(&l), dl);
}

// ------- Kernel 2: r6-core 256^2 8-phase GEMM (K=1024) + histogram + contention-free finalize -------
__global__ __launch_bounds__(512, 2) void gemm_stat_k(const __bf16* __restrict__ u,
                                                      const int* __restrict__ targets,
                                                      const float* __restrict__ acc_sum,
                                                      float* __restrict__ part,
                                                      int* __restrict__ ticket,
                                                      float* __restrict__ out) {
    // [slot][A=0/B=1][half][128 rows x 64 cols], rows 128B, XOR-swizzled storage
    __shared__ __align__(16) __bf16 lds[2][2][2][128 * 64];
    __shared__ int tgtR[256], tgtC[256];
    __shared__ float red_s[8][10], red_c[8][10];
    __shared__ float tot[20];
    __shared__ int is_last;

    const int bid = blockIdx.x;
    const int swz = (bid & 7) * 32 + (bid >> 3);  // 256 blocks, 8 XCDs, bijective
    const int by = swz >> 4, bx = swz & 15;
    const int row0 = by * 256, col0 = bx * 256;
    const int tid = threadIdx.x, lane = tid & 63;
    const int wid = tid >> 6, wr = wid >> 2, wc = wid & 3;  // 2 x 4 waves

    if (tid < 256) tgtR[tid] = targets[row0 + tid];
    else           tgtC[tid - 256] = targets[col0 + tid - 256];

    // staging: half-tile = 128x64 bf16 = 1024 x 16B chunks; thread handles chunks tid, tid+512
    const int c0 = tid, c1 = tid + 512;
    const int r0c = c0 >> 3, x0 = ((c0 & 7) ^ (r0c & 7)) * 8;  // inverse-swizzled source col
    const int r1c = c1 >> 3, x1 = ((c1 & 7) ^ (r1c & 7)) * 8;

    auto STAGE = [&](int s) {  // s = half-tile stream position, 0..63
        const int kt = s >> 2, h4 = s & 3;  // h4: 0,1 = A-half; 2,3 = B-half
        const int slot = kt & 1, kcol = kt * 64;
        const bool isA = (h4 < 2);
        const int half = h4 & 1;
        const int brow = (isA ? row0 : col0) + half * 128;
        __bf16* ldst = &lds[slot][isA ? 0 : 1][half][0];
        GLOAD16(u + (size_t)(brow + r0c) * NDU + kcol + x0, ldst + c0 * 8);
        GLOAD16(u + (size_t)(brow + r1c) * NDU + kcol + x1, ldst + c1 * 8);
    };

    const f32x4 fzero = {0.0f, 0.0f, 0.0f, 0.0f};
    f32x4 acc[8][4];
#pragma unroll
    for (int a = 0; a < 8; ++a)
#pragma unroll
        for (int n = 0; n < 4; ++n) acc[a][n] = fzero;

    // prologue: kt0's 4 half-tiles + kt1.A0 in flight
    STAGE(0); STAGE(1); STAGE(2); STAGE(3); STAGE(4);
    asm volatile("s_waitcnt vmcnt(2)" ::: "memory");  // kt0 fully resident
    __builtin_amdgcn_s_barrier();
    __builtin_amdgcn_sched_barrier(0);

    const int fr = lane & 15, hi16 = lane >> 4;
    const int Bhalf = wc >> 1;

    for (int kt = 0; kt < NKT; ++kt) {
        const int slot = kt & 1;
        const __bf16* lA = &lds[slot][0][0][0];
        const __bf16* lB = &lds[slot][1][Bhalf][0];
#pragma unroll
        for (int f = 0; f < 4; ++f) {  // quadrant phase: (Mhalf, khalf)
            const int Mh = f >> 1, kh = f & 1;
            bf16x8 af[4], bf[4];
#pragma unroll
            for (int q = 0; q < 4; ++q) {
                const int row = wr * 64 + q * 16 + fr;
                const int cb = (kh * 64 + hi16 * 16) ^ ((row & 7) << 4);
                af[q] = *(const bf16x8*)((const char*)(lA + Mh * 8192) + row * 128 + cb);
            }
#pragma unroll
            for (int n = 0; n < 4; ++n) {
                const int row = (wc & 1) * 64 + n * 16 + fr;
                const int cb = (kh * 64 + hi16 * 16) ^ ((row & 7) << 4);
                bf[n] = *(const bf16x8*)((const char*)lB + row * 128 + cb);
            }
            const int s = 4 * kt + f + 5;  // issue 5 half-tiles ahead
            if (s < 4 * NKT) STAGE(s);
            __builtin_amdgcn_s_barrier();  // B1
            __builtin_amdgcn_sched_barrier(0);
            __builtin_amdgcn_s_setprio(1);
#pragma unroll
            for (int q = 0; q < 4; ++q)
#pragma unroll
                for (int n = 0; n < 4; ++n)
                    acc[Mh * 4 + q][n] = __builtin_amdgcn_mfma_f32_16x16x32_bf16(
                        af[q], bf[n], acc[Mh * 4 + q][n], 0, 0, 0);
            __builtin_amdgcn_s_setprio(0);
            __builtin_amdgcn_sched_barrier(0);
            if (f == 3) {  // K-tile boundary: next tile's halves must be resident
                if (kt < NKT - 2)       asm volatile("s_waitcnt vmcnt(2)" ::: "memory");
                else if (kt == NKT - 2) asm volatile("s_waitcnt vmcnt(0)" ::: "memory");
            }
            __builtin_amdgcn_s_barrier();  // B2
            __builtin_amdgcn_sched_barrier(0);
        }
    }

    // ---- epilogue: per-lane histogram of g=|cos-label| over 128 elements ----
    int tcv[4];
#pragma unroll
    for (int n = 0; n < 4; ++n) tcv[n] = tgtC[wc * 64 + n * 16 + fr];

    constexpr float E[11] = {0.0f, 0.1f, 0.2f, 0.3f, 0.4f, 0.5f,
                             0.6f, 0.7f, 0.8f, 0.9f, 1.0f + 1e-6f};
    float sacc[10], cacc[10];
#pragma unroll
    for (int b = 0; b < 10; ++b) { sacc[b] = 0.0f; cacc[b] = 0.0f; }

    const int rB = wr * 64 + hi16 * 4;
#pragma unroll
    for (int a = 0; a < 8; ++a) {
        int trv[4];
#pragma unroll
        for (int r = 0; r < 4; ++r) trv[r] = tgtR[(a >> 2) * 128 + rB + (a & 3) * 16 + r];
#pragma unroll
        for (int n = 0; n < 4; ++n) {
            f32x4 v = acc[a][n];
            const int tc = tcv[n];
#pragma unroll
            for (int r = 0; r < 4; ++r) {
                const float label = (trv[r] == tc) ? 1.0f : 0.0f;
                const float g = fabsf(v[r] - label);
                const float g2 = g * g;
                bool prev = true;
#pragma unroll
                for (int b = 0; b < 10; ++b) {
                    const bool ge = (g >= E[b + 1]);
                    const bool in = prev && (!ge);
                    sacc[b] += in ? g2 : 0.0f;
                    cacc[b] += in ? 1.0f : 0.0f;
                    prev = ge;
                }
            }
        }
    }

#pragma unroll
    for (int b = 0; b < 10; ++b) {
        float sv = sacc[b], cv = cacc[b];
#pragma unroll
        for (int off = 32; off > 0; off >>= 1) {
            sv += __shfl_xor(sv, off);
            cv += __shfl_xor(cv, off);
        }
        if (lane == 0) { red_s[wid][b] = sv; red_c[wid][b] = cv; }
    }
    __syncthreads();

    // ---- contention-free partials: device-scope stores to DISTINCT slots ----
    if (tid < 10) {
        float s = 0.0f, c = 0.0f;
#pragma unroll
        for (int w = 0; w < 8; ++w) { s += red_s[w][tid]; c += red_c[w][tid]; }
        __hip_atomic_store(&part[tid * NBLK + bid], s,
                           __ATOMIC_RELAXED, __HIP_MEMORY_SCOPE_AGENT);
        __hip_atomic_store(&part[(10 + tid) * NBLK + bid], c,
                           __ATOMIC_RELAXED, __HIP_MEMORY_SCOPE_AGENT);
    }
    __syncthreads();  // drains each wave's vmcnt -> stores at coherence point

    if (tid == 0) {
        int old = __hip_atomic_fetch_add(ticket, 1, __ATOMIC_ACQ_REL,
                                         __HIP_MEMORY_SCOPE_AGENT);
        is_last = (old == NBLK - 1) ? 1 : 0;
    }
    __syncthreads();

    // ---- last block: parallel-reduce the 20x256 partials, compute loss ----
    if (is_last) {
        for (int b = wid; b < 20; b += 8) {
            float v = 0.0f;
#pragma unroll
            for (int j = 0; j < 4; ++j)
                v += __hip_atomic_load(&part[b * NBLK + lane + 64 * j],
                                       __ATOMIC_RELAXED, __HIP_MEMORY_SCOPE_AGENT);
#pragma unroll
            for (int off = 32; off > 0; off >>= 1) v += __shfl_xor(v, off);
            if (lane == 0) tot[b] = v;
        }
        __syncthreads();
        if (tid == 0) {
            const float totN = 16777216.0f;  // 4096^2
            double num = 0.0, valid = 0.0;
#pragma unroll
            for (int b = 0; b < 10; ++b) {
                float cnt = tot[10 + b];
                float accn = 0.5f * acc_sum[b] + 0.5f * cnt;
                float w = totN / (accn + 1e-6f);
                num += (double)tot[b] * (double)w;
                valid += (double)cnt;
            }
            out[0] = (valid > 0.0) ? (float)(num / valid / 16777216.0) : 0.0f;
        }
    }
}

extern "C" void kernel_launch(void* const* d_in, const int* in_sizes, int n_in,
                              void* d_out, int out_size, void* d_ws, size_t ws_size,
                              hipStream_t stream) {
    const float* x = (const float*)d_in[0];
    const float* acc_sum = (const float*)d_in[1];
    const int* targets = (const int*)d_in[2];
    float* out = (float*)d_out;

    char* ws = (char*)d_ws;
    __bf16* u = (__bf16*)ws;                                   // 4096 x 1024 bf16 = 8 MB
    float* part = (float*)(ws + (size_t)NB * NDU * sizeof(__bf16));  // 20 x 256 partials
    int* ticket = (int*)(part + 20 * NBLK);

    nrm_split_k<<<NB / 4, 256, 0, stream>>>(x, u, part, ticket);
    gemm_stat_k<<<NBLK, 512, 0, stream>>>(u, targets, acc_sum, part, ticket, out);
}